// Round 2
// baseline (5045.331 us; speedup 1.0000x reference)
//
#include <hip/hip_runtime.h>
#include <math.h>

// ---------------------------------------------------------------------------
// 2-step recurrent attention cell, N=8, I=128, C=Hc=A=P=O=256, H=W=40
// (Q=1600), VALID 3x3 -> 38x38 (D=1444). fp32.
//
// Exact algebraic reductions (see round-0 notes):
//  * step1 h uniform -> k_h/v_h constant over d; (1,1) softmax uniform;
//    q_h has 9 padding-validity classes -> h_new piecewise-constant (9 classes)
//  * step2 k_h2/v_h2 classed (mult {1,36,1}^2) -> (0,1) attention collapses
//  * step2 q_h/gates dead; step1 a_x/out dead.
// Heavy work: fused qkv conv (45 GF), (0,0) attention (19 GF), out conv (5 GF).
//
// R2: gemm128 (128x128 tile, 8x8 microtile, split-fragment mapping for <=2-way
// LDS banking), q/k/v weights concatenated -> single conv GEMM.
// ---------------------------------------------------------------------------

// Y[b](m,n) = sum_k A[b](m,k)*B[b](k,n) (+ bias[m])
// 128x128 tile, 256 threads, 8x8/thread. Thread covers rows
// {ty*4+i, ty*4+64+i} x cols {tx*4+j, tx*4+64+j}.
// aMc: A loader walks m contiguously (use when sAm==1), else k. bNc: same for B.
// Grid: (ceil(M/128), ceil(N/128), batch) -- m-tile fastest for B L2 reuse.
__global__ __launch_bounds__(256) void gemm128(
    const float* __restrict__ A, long sAm, long sAk, long sAb,
    const float* __restrict__ B, long sBk, long sBn, long sBb,
    float* __restrict__ Y, long sYm, long sYn, long sYb,
    const float* __restrict__ bias,
    int M, int Nn, int K, int aMc, int bNc)
{
  __shared__ __align__(16) float As[16][132];   // 132*4B row = 16B-aligned, %32 banks = 4
  __shared__ __align__(16) float Bs[16][132];
  const int bz = blockIdx.z;
  A += (long)bz * sAb; B += (long)bz * sBb; Y += (long)bz * sYb;
  const int m0 = blockIdx.x * 128, n0 = blockIdx.y * 128;
  const int tid = threadIdx.x;
  const int tx = tid & 15, ty = tid >> 4;
  float acc[8][8];
  #pragma unroll
  for (int i = 0; i < 8; ++i)
    #pragma unroll
    for (int j = 0; j < 8; ++j) acc[i][j] = 0.f;

  for (int k0 = 0; k0 < K; k0 += 16) {
    if (aMc) {
      #pragma unroll
      for (int i = tid; i < 2048; i += 256) {
        int m = i & 127, kk = i >> 7;
        int mm = m0 + m, kg = k0 + kk;
        As[kk][m] = (mm < M && kg < K) ? A[(long)mm * sAm + (long)kg * sAk] : 0.f;
      }
    } else {
      #pragma unroll
      for (int i = tid; i < 2048; i += 256) {
        int kk = i & 15, m = i >> 4;
        int mm = m0 + m, kg = k0 + kk;
        As[kk][m] = (mm < M && kg < K) ? A[(long)mm * sAm + (long)kg * sAk] : 0.f;
      }
    }
    if (bNc) {
      #pragma unroll
      for (int i = tid; i < 2048; i += 256) {
        int n = i & 127, kk = i >> 7;
        int nn = n0 + n, kg = k0 + kk;
        Bs[kk][n] = (nn < Nn && kg < K) ? B[(long)kg * sBk + (long)nn * sBn] : 0.f;
      }
    } else {
      #pragma unroll
      for (int i = tid; i < 2048; i += 256) {
        int kk = i & 15, n = i >> 4;
        int nn = n0 + n, kg = k0 + kk;
        Bs[kk][n] = (nn < Nn && kg < K) ? B[(long)kg * sBk + (long)nn * sBn] : 0.f;
      }
    }
    __syncthreads();
    #pragma unroll
    for (int kk = 0; kk < 16; ++kk) {
      float4 a0 = *(const float4*)&As[kk][ty * 4];
      float4 a1 = *(const float4*)&As[kk][ty * 4 + 64];
      float4 b0 = *(const float4*)&Bs[kk][tx * 4];
      float4 b1 = *(const float4*)&Bs[kk][tx * 4 + 64];
      float av[8] = {a0.x, a0.y, a0.z, a0.w, a1.x, a1.y, a1.z, a1.w};
      float bv[8] = {b0.x, b0.y, b0.z, b0.w, b1.x, b1.y, b1.z, b1.w};
      #pragma unroll
      for (int i = 0; i < 8; ++i)
        #pragma unroll
        for (int j = 0; j < 8; ++j) acc[i][j] += av[i] * bv[j];
    }
    __syncthreads();
  }
  #pragma unroll
  for (int i = 0; i < 8; ++i) {
    int mm = m0 + ((i < 4) ? (ty * 4 + i) : (ty * 4 + 64 + i - 4));
    if (mm >= M) continue;
    float bb = bias ? bias[mm] : 0.f;
    #pragma unroll
    for (int j = 0; j < 8; ++j) {
      int nn = n0 + ((j < 4) ? (tx * 4 + j) : (tx * 4 + 64 + j - 4));
      if (nn < Nn) Y[(long)mm * sYm + (long)nn * sYn] = acc[i][j] + bb;
    }
  }
}

// concat w_qx|w_kx|w_vx -> wcat[768][2304]
__global__ __launch_bounds__(256) void concat_w(
    const float* __restrict__ wq, const float* __restrict__ wk,
    const float* __restrict__ wv, float* __restrict__ wcat)
{
  int i = blockIdx.x * 256 + threadIdx.x;
  if (i >= 768 * 2304) return;
  int r = i / 2304;
  wcat[i] = (r < 256) ? wq[i] : (r < 512) ? wk[i - 256 * 2304] : wv[i - 512 * 2304];
}

// im2col for SAME 3x3 over xp (channels 0..255 of xa)
__global__ __launch_bounds__(256) void im2col_same(
    const float* __restrict__ xa, float* __restrict__ icol, int nb, long total)
{
  long i = (long)blockIdx.x * 256 + threadIdx.x;
  if (i >= total) return;
  int q = (int)(i % 1600); long r = i / 1600;
  int k = (int)(r % 2304); int nn = (int)(r / 2304);
  int c = k / 9, tap = k - c * 9;
  int dy = tap / 3, dx = tap - dy * 3;
  int qy = q / 40, qx = q - qy * 40;
  int y = qy + dy - 1, x = qx + dx - 1;
  float v = 0.f;
  if (y >= 0 && y < 40 && x >= 0 && x < 40)
    v = xa[(long)(nb + nn) * 1228800 + (long)c * 1600 + y * 40 + x];
  icol[i] = v;
}

// crop qkv channels 256..767 (SAME-layout interior) -> VALID-indexed kx/vx
__global__ __launch_bounds__(256) void crop_kv(
    const float* __restrict__ src, float* __restrict__ kx, float* __restrict__ vx,
    long total)
{
  long i = (long)blockIdx.x * 256 + threadIdx.x;
  if (i >= total) return;
  int d = (int)(i % 1444); long r = i / 1444;
  int cc = (int)(r % 512); int n = (int)(r / 512);
  int yv = d / 38, xv = d - yv * 38;
  float v = src[(long)n * 1228800 + (long)(256 + cc) * 1600 + (yv + 1) * 40 + (xv + 1)];
  if (cc < 256) kx[(long)n * 369664 + (long)cc * 1444 + d] = v;
  else          vx[(long)n * 369664 + (long)(cc - 256) * 1444 + d] = v;
}

// step-1 uniform-h class tables: j<9 -> q_h1[j][a]; j==9 -> k_h1[a]; j==10 -> v_h1[a]
__global__ __launch_bounds__(64) void uniform_kv_kern(
    const float* __restrict__ h0, const float* __restrict__ w_qh,
    const float* __restrict__ w_kh, const float* __restrict__ w_vh,
    float* __restrict__ qh1, float* __restrict__ kh1, float* __restrict__ vh1)
{
  int a = blockIdx.x, j = blockIdx.y, t = threadIdx.x;
  const float* wsel = (j < 9) ? w_qh : (j == 9) ? w_kh : w_vh;
  bool dyok0 = true, dyok2 = true, dxok0 = true, dxok2 = true;
  if (j < 9) {
    int uy = j / 3, ux = j - uy * 3;
    dyok0 = (uy != 0); dyok2 = (uy != 2);
    dxok0 = (ux != 0); dxok2 = (ux != 2);
  }
  float acc = 0.f;
  for (int c = t; c < 256; c += 64) {
    const float* wp = wsel + a * 2304 + c * 9;
    float s = 0.f;
    #pragma unroll
    for (int dy = 0; dy < 3; ++dy) {
      if ((dy == 0 && !dyok0) || (dy == 2 && !dyok2)) continue;
      #pragma unroll
      for (int dx = 0; dx < 3; ++dx) {
        if ((dx == 0 && !dxok0) || (dx == 2 && !dxok2)) continue;
        s += wp[dy * 3 + dx];
      }
    }
    acc += s * h0[c];
  }
  #pragma unroll
  for (int o = 32; o; o >>= 1) acc += __shfl_down(acc, o);
  if (t == 0) {
    if (j < 9) qh1[j * 256 + a] = acc;
    else if (j == 9) kh1[a] = acc;
    else vh1[a] = acc;
  }
}

// row softmax (in place)
__global__ __launch_bounds__(256) void softmax_rows(float* __restrict__ p, int L)
{
  float* r = p + (long)blockIdx.x * L;
  int t = threadIdx.x;
  __shared__ float redm[4], reds[4];
  float mx = -3.4e38f;
  for (int i = t; i < L; i += 256) mx = fmaxf(mx, r[i]);
  #pragma unroll
  for (int o = 32; o; o >>= 1) mx = fmaxf(mx, __shfl_down(mx, o));
  if ((t & 63) == 0) redm[t >> 6] = mx;
  __syncthreads();
  mx = fmaxf(fmaxf(redm[0], redm[1]), fmaxf(redm[2], redm[3]));
  float s = 0.f;
  for (int i = t; i < L; i += 256) { float v = expf(r[i] - mx); r[i] = v; s += v; }
  #pragma unroll
  for (int o = 32; o; o >>= 1) s += __shfl_down(s, o);
  if ((t & 63) == 0) reds[t >> 6] = s;
  __syncthreads();
  float inv = 1.f / (reds[0] + reds[1] + reds[2] + reds[3]);
  for (int i = t; i < L; i += 256) r[i] *= inv;
}

// gate input vector: [a10 ; v_h1] laid out [n][k512][u9]
__global__ __launch_bounds__(256) void build_vecb(
    const float* __restrict__ a10, const float* __restrict__ vh1,
    float* __restrict__ vecb)
{
  int i = blockIdx.x * 256 + threadIdx.x;
  if (i >= 8 * 512 * 9) return;
  int u = i % 9; int k = (i / 9) % 512; int n = i / 4608;
  vecb[i] = (k < 256) ? a10[n * 2304 + u * 256 + k] : vh1[k - 256];
}

// h1 = z*h0 + (1-z)*tanh(hpre), classed [n][hc][u9]
__global__ __launch_bounds__(256) void gate_ew(
    const float* __restrict__ zpre, const float* __restrict__ hpre,
    const float* __restrict__ h0, float* __restrict__ h1)
{
  int i = blockIdx.x * 256 + threadIdx.x;
  if (i >= 8 * 256 * 9) return;
  int hc = (i % 2304) / 9;
  float z = 1.f / (1.f + expf(-zpre[i]));
  float hv = tanhf(hpre[i]);
  h1[i] = z * h0[hc] + (1.f - z) * hv;
}

// classed im2col for step-2 VALID conv over piecewise-constant h1
__global__ __launch_bounds__(256) void build_G(
    const float* __restrict__ h1, float* __restrict__ G)
{
  int i = blockIdx.x * 256 + threadIdx.x;
  if (i >= 8 * 2304 * 9) return;
  int t = i % 9; int k = (i / 9) % 2304; int n = i / 20736;
  int c = k / 9, tap = k - c * 9, dy = tap / 3, dx = tap - dy * 3;
  int ty = t / 3, tx = t - ty * 3;
  int uy = (ty == 0) ? (dy == 0 ? 0 : 1) : (ty == 2) ? (dy == 2 ? 2 : 1) : 1;
  int ux = (tx == 0) ? (dx == 0 ? 0 : 1) : (tx == 2) ? (dx == 2 ? 2 : 1) : 1;
  G[i] = h1[n * 2304 + c * 9 + uy * 3 + ux];
}

// step-2 (a=0,b=1) classed attention: 9 logits/query, mult {1,36,1}^2
__global__ __launch_bounds__(256) void attn_b1(
    const float* __restrict__ qkv, const float* __restrict__ khc,
    const float* __restrict__ vhc, float* __restrict__ xa)
{
  __shared__ float ks[2304];
  __shared__ float vs[2304];
  int n = blockIdx.y;
  int q = blockIdx.x * 256 + threadIdx.x;
  const float* kp = khc + n * 2304;
  const float* vp = vhc + n * 2304;
  for (int i = threadIdx.x; i < 2304; i += 256) { ks[i] = kp[i]; vs[i] = vp[i]; }
  __syncthreads();
  bool act = (q < 1600);
  float L[9] = {0.f, 0.f, 0.f, 0.f, 0.f, 0.f, 0.f, 0.f, 0.f};
  const float* qp = qkv + (long)n * 1228800 + q;   // channels 0..255 = q_x
  for (int c = 0; c < 256; ++c) {
    float qv = act ? qp[(long)c * 1600] : 0.f;
    #pragma unroll
    for (int t = 0; t < 9; ++t) L[t] += qv * ks[c * 9 + t];
  }
  float mx = L[0];
  #pragma unroll
  for (int t = 1; t < 9; ++t) mx = fmaxf(mx, L[t]);
  float e[9]; float Z = 0.f;
  #pragma unroll
  for (int t = 0; t < 9; ++t) {
    float m = ((t / 3) == 1 ? 36.f : 1.f) * ((t % 3) == 1 ? 36.f : 1.f);
    e[t] = m * expf(L[t] - mx);
    Z += e[t];
  }
  float inv = 1.f / Z;
  #pragma unroll
  for (int t = 0; t < 9; ++t) e[t] *= inv;
  float* op = xa + (long)n * 1228800 + 819200 + q;   // channels 512..767
  for (int p = 0; p < 256; ++p) {
    float s = 0.f;
    #pragma unroll
    for (int t = 0; t < 9; ++t) s += e[t] * vs[p * 9 + t];
    if (act) op[(long)p * 1600] = s;
  }
}

// ---------------------------------------------------------------------------
extern "C" void kernel_launch(void* const* d_in, const int* in_sizes, int n_in,
                              void* d_out, int out_size, void* d_ws, size_t ws_size,
                              hipStream_t stream)
{
  const float* x     = (const float*)d_in[0];
  const float* h0    = (const float*)d_in[1];
  const float* w_px  = (const float*)d_in[2];
  const float* b_px  = (const float*)d_in[3];
  const float* w_qx  = (const float*)d_in[4];
  const float* w_qh  = (const float*)d_in[5];
  const float* w_kx  = (const float*)d_in[6];
  const float* w_kh  = (const float*)d_in[7];
  const float* w_vx  = (const float*)d_in[8];
  const float* w_vh  = (const float*)d_in[9];
  const float* w_z   = (const float*)d_in[10];
  const float* b_z   = (const float*)d_in[11];
  const float* w_h   = (const float*)d_in[12];
  const float* b_h   = (const float*)d_in[13];
  const float* w_out = (const float*)d_in[14];
  const float* b_out = (const float*)d_in[15];
  float* out = (float*)d_out;
  float* ws  = (float*)d_ws;

  size_t off = 0;
  auto alloc = [&](size_t n) { size_t o = off; off += (n + 63) & ~(size_t)63; return o; };
  float* xa   = ws + alloc((size_t)8 * 768 * 1600);   // [n][768]: xp | a00 | a01
  float* qkv  = ws + alloc((size_t)8 * 768 * 1600);   // [n][768]: q_x | k(SAME) | v(SAME)
  float* kx   = ws + alloc((size_t)8 * 256 * 1444);
  float* vx   = ws + alloc((size_t)8 * 256 * 1444);
  float* wcat = ws + alloc((size_t)768 * 2304);
  float* qh1  = ws + alloc(9 * 256);
  float* kh1  = ws + alloc(256);
  float* vh1  = ws + alloc(256);
  float* L0   = ws + alloc((size_t)8 * 9 * 1444);
  float* a10  = ws + alloc((size_t)8 * 9 * 256);
  float* vecb = ws + alloc((size_t)8 * 512 * 9);
  float* zpre = ws + alloc((size_t)8 * 256 * 9);
  float* hpre = ws + alloc((size_t)8 * 256 * 9);
  float* h1   = ws + alloc((size_t)8 * 256 * 9);
  float* G    = ws + alloc((size_t)8 * 2304 * 9);
  float* khc  = ws + alloc((size_t)8 * 256 * 9);
  float* vhc  = ws + alloc((size_t)8 * 256 * 9);
  float* scratch = ws + off;
  long avail_f = (long)(ws_size / 4) - (long)off;
  if (avail_f < 0) avail_f = 0;
  int cn = (int)(avail_f / 3686400L); if (cn < 1) cn = 1; if (cn > 8) cn = 8;
  int an = (int)(avail_f / 2310400L); if (an < 1) an = 1; if (an > 8) an = 8;

  auto gemm = [&](dim3 grid,
                  const float* A, long sAm, long sAk, long sAb,
                  const float* B, long sBk, long sBn, long sBb,
                  float* Y, long sYm, long sYn, long sYb,
                  const float* bias, int M, int Nn, int K, int aMc, int bNc) {
    gemm128<<<grid, dim3(256), 0, stream>>>(A, sAm, sAk, sAb, B, sBk, sBn, sBb,
                                            Y, sYm, sYn, sYb, bias, M, Nn, K, aMc, bNc);
  };

  // 1) xp = w_px . x + b_px -> xa channels 0..255
  gemm(dim3(2, 13, 8), w_px, 128, 1, 0, x, 1600, 1, 204800,
       xa, 1600, 1, 1228800, b_px, 256, 1600, 128, 0, 1);

  // 2) fused qkv conv: wcat[768][2304] . im2col(xp)
  concat_w<<<dim3(6912), dim3(256), 0, stream>>>(w_qx, w_kx, w_vx, wcat);
  for (int nb = 0; nb < 8; nb += cn) {
    int c = (8 - nb < cn) ? (8 - nb) : cn;
    long tot = (long)c * 3686400;
    im2col_same<<<dim3((unsigned)((tot + 255) / 256)), dim3(256), 0, stream>>>(xa, scratch, nb, tot);
    gemm(dim3(6, 13, c), wcat, 2304, 1, 0, scratch, 1600, 1, 3686400,
         qkv + (size_t)nb * 1228800, 1600, 1, 1228800, nullptr, 768, 1600, 2304, 0, 1);
    long ctot = (long)c * 512 * 1444;
    crop_kv<<<dim3((unsigned)((ctot + 255) / 256)), dim3(256), 0, stream>>>(
        qkv + (size_t)nb * 1228800, kx + (size_t)nb * 369664, vx + (size_t)nb * 369664, ctot);
  }

  // 3) step-1 class tables + classed attention + gates
  uniform_kv_kern<<<dim3(256, 11), dim3(64), 0, stream>>>(h0, w_qh, w_kh, w_vh, qh1, kh1, vh1);
  gemm(dim3(1, 12, 8), qh1, 256, 1, 0, kx, 1444, 1, 369664,
       L0, 1444, 1, 12996, nullptr, 9, 1444, 256, 0, 1);
  softmax_rows<<<dim3(72), dim3(256), 0, stream>>>(L0, 1444);
  gemm(dim3(2, 1, 8), vx, 1444, 1, 369664, L0, 1, 1444, 12996,
       a10, 1, 256, 2304, nullptr, 256, 9, 1444, 0, 0);
  build_vecb<<<dim3(144), dim3(256), 0, stream>>>(a10, vh1, vecb);
  gemm(dim3(2, 1, 8), w_z, 512, 1, 0, vecb, 9, 1, 4608,
       zpre, 9, 1, 2304, b_z, 256, 9, 512, 0, 1);
  gemm(dim3(2, 1, 8), w_h, 512, 1, 0, vecb, 9, 1, 4608,
       hpre, 9, 1, 2304, b_h, 256, 9, 512, 0, 1);
  gate_ew<<<dim3(72), dim3(256), 0, stream>>>(zpre, hpre, h0, h1);

  // 4) step-2 classed k_h2/v_h2 + classed attention -> xa channels 512..767
  build_G<<<dim3(648), dim3(256), 0, stream>>>(h1, G);
  gemm(dim3(2, 1, 8), w_kh, 2304, 1, 0, G, 9, 1, 20736,
       khc, 9, 1, 2304, nullptr, 256, 9, 2304, 0, 1);
  gemm(dim3(2, 1, 8), w_vh, 2304, 1, 0, G, 9, 1, 20736,
       vhc, 9, 1, 2304, nullptr, 256, 9, 2304, 0, 1);
  attn_b1<<<dim3(7, 8), dim3(256), 0, stream>>>(qkv, khc, vhc, xa);

  // 5) step-2 (a=0,b=0) full attention -> xa channels 256..511
  for (int nb = 0; nb < 8; nb += an) {
    int c = (8 - nb < an) ? (8 - nb) : an;
    gemm(dim3(13, 12, c), qkv + (size_t)nb * 1228800, 1, 1600, 1228800,
         kx + (size_t)nb * 369664, 1444, 1, 369664,
         scratch, 1444, 1, 2310400, nullptr, 1600, 1444, 256, 1, 1);
    softmax_rows<<<dim3(c * 1600), dim3(256), 0, stream>>>(scratch, 1444);
    gemm(dim3(2, 13, c), vx + (size_t)nb * 369664, 1444, 1, 369664,
         scratch, 1, 1444, 2310400,
         xa + (size_t)nb * 1228800 + 409600, 1600, 1, 1228800,
         nullptr, 256, 1600, 1444, 0, 0);
  }

  // 6) out = w_out . [xp; a00; a01] + b_out
  gemm(dim3(2, 13, 8), w_out, 768, 1, 0, xa, 1600, 1, 1228800,
       out, 1600, 1, 409600, b_out, 256, 1600, 768, 0, 1);
}

// Round 3
// 2002.684 us; speedup vs baseline: 2.5193x; 2.5193x over previous
//
#include <hip/hip_runtime.h>
#include <math.h>

// ---------------------------------------------------------------------------
// 2-step recurrent attention cell, N=8, I=128, C=Hc=A=P=O=256, H=W=40
// (Q=1600), VALID 3x3 -> 38x38 (D=1444). fp32 reference.
//
// Exact algebraic reductions (rounds 0-2): step1 h uniform -> classed tables;
// step2 (0,1) attention collapses to 9 key classes; dead branches removed.
// R3: all heavy GEMMs moved to MFMA via split-bf16 (f32 = hi + lo bf16,
// 3 MFMA products AhBh+AhBl+AlBh; AlBl ~2^-16 rel, negligible).
// Operands pre-converted to bf16 hi/lo planes, [rows][K] k-contig, K%32==0.
// ---------------------------------------------------------------------------

typedef __attribute__((ext_vector_type(8))) short bf8;   // 8 bf16 (4 VGPRs)
typedef __attribute__((ext_vector_type(4))) float f4;

__device__ __forceinline__ ushort f2bf(float f) {
  unsigned u = __float_as_uint(f);
  u += 0x7fffu + ((u >> 16) & 1u);
  return (ushort)(u >> 16);
}
__device__ __forceinline__ float bf2f(ushort h) {
  return __uint_as_float(((unsigned)h) << 16);
}

// ---------------- MFMA split-bf16 GEMM ----------------
// C[m][n] = sum_k A[m][k]*B[n][k]  (both operands k-contig "row" layout)
// A planes [M][K], B planes [N][K], K multiple of 32 (zero-padded by producer).
// 128x128 tile, 4 waves, wave = 64x64 quadrant of 16x16x32 MFMA tiles.
// Store: fp32 mode (Yh==null): addr = bz*sYb + (nn/nPer)*sYb2 + mm*sYm + nn%nPer
//        pair mode: bf16 hi/lo planes at bz*sYpb + mm*sYpm + nn.
// Grid: (mtiles, ntiles, batch) -- m fastest so consecutive blocks share B tile.
__global__ __launch_bounds__(256) void mgemm(
    const ushort* __restrict__ Ah, const ushort* __restrict__ Al, long sAb,
    const ushort* __restrict__ Bh, const ushort* __restrict__ Bl, long sBb,
    float* __restrict__ Y, long sYb, long sYm, int nPer, long sYb2,
    ushort* __restrict__ Yh, ushort* __restrict__ Yl, long sYpb, long sYpm,
    const float* __restrict__ bias, int M, int Nn, int K)
{
  __shared__ ushort Ash[128][40], Asl[128][40], Bsh[128][40], Bsl[128][40];
  const int bz = blockIdx.z;
  Ah += (long)bz * sAb; Al += (long)bz * sAb;
  Bh += (long)bz * sBb; Bl += (long)bz * sBb;
  const int m0 = blockIdx.x * 128, n0 = blockIdx.y * 128;
  const int t = threadIdx.x;
  const int lane = t & 63, w = t >> 6;
  const int wm = (w & 1) * 64, wn = (w >> 1) * 64;
  const int r = lane & 15, qd = lane >> 4;
  const int row0 = t >> 2, seg = t & 3;
  f4 acc[4][4];
  #pragma unroll
  for (int i = 0; i < 4; ++i)
    #pragma unroll
    for (int j = 0; j < 4; ++j) acc[i][j] = (f4){0.f, 0.f, 0.f, 0.f};

  for (int kc = 0; kc < K; kc += 32) {
    #pragma unroll
    for (int half = 0; half < 2; ++half) {
      int row = row0 + half * 64;
      {
        int mm = m0 + row;
        uint4 vh = make_uint4(0,0,0,0), vl = make_uint4(0,0,0,0);
        if (mm < M) {
          size_t o = (size_t)mm * K + kc + seg * 8;
          vh = *(const uint4*)(Ah + o);
          vl = *(const uint4*)(Al + o);
        }
        *(uint4*)&Ash[row][seg * 8] = vh;
        *(uint4*)&Asl[row][seg * 8] = vl;
      }
      {
        int nn = n0 + row;
        uint4 vh = make_uint4(0,0,0,0), vl = make_uint4(0,0,0,0);
        if (nn < Nn) {
          size_t o = (size_t)nn * K + kc + seg * 8;
          vh = *(const uint4*)(Bh + o);
          vl = *(const uint4*)(Bl + o);
        }
        *(uint4*)&Bsh[row][seg * 8] = vh;
        *(uint4*)&Bsl[row][seg * 8] = vl;
      }
    }
    __syncthreads();
    bf8 ahf[4], alf[4], bhf[4], blf[4];
    #pragma unroll
    for (int mt = 0; mt < 4; ++mt) {
      ahf[mt] = *(const bf8*)&Ash[wm + mt * 16 + r][qd * 8];
      alf[mt] = *(const bf8*)&Asl[wm + mt * 16 + r][qd * 8];
      bhf[mt] = *(const bf8*)&Bsh[wn + mt * 16 + r][qd * 8];
      blf[mt] = *(const bf8*)&Bsl[wn + mt * 16 + r][qd * 8];
    }
    #pragma unroll
    for (int mt = 0; mt < 4; ++mt)
      #pragma unroll
      for (int nt = 0; nt < 4; ++nt) {
        acc[mt][nt] = __builtin_amdgcn_mfma_f32_16x16x32_bf16(ahf[mt], bhf[nt], acc[mt][nt], 0, 0, 0);
        acc[mt][nt] = __builtin_amdgcn_mfma_f32_16x16x32_bf16(ahf[mt], blf[nt], acc[mt][nt], 0, 0, 0);
        acc[mt][nt] = __builtin_amdgcn_mfma_f32_16x16x32_bf16(alf[mt], bhf[nt], acc[mt][nt], 0, 0, 0);
      }
    __syncthreads();
  }
  #pragma unroll
  for (int mt = 0; mt < 4; ++mt)
    #pragma unroll
    for (int nt = 0; nt < 4; ++nt) {
      int nn = n0 + wn + nt * 16 + r;
      #pragma unroll
      for (int e = 0; e < 4; ++e) {
        int mm = m0 + wm + mt * 16 + qd * 4 + e;
        if (mm >= M || nn >= Nn) continue;
        float v = acc[mt][nt][e];
        if (Yh) {
          size_t o = (size_t)bz * sYpb + (size_t)mm * sYpm + nn;
          ushort h = f2bf(v);
          Yh[o] = h;
          Yl[o] = f2bf(v - bf2f(h));
        } else {
          int nb = nn / nPer, nq = nn - nb * nPer;
          if (bias) v += bias[mm];
          Y[(size_t)bz * sYb + (size_t)nb * sYb2 + (size_t)mm * sYm + nq] = v;
        }
      }
    }
}

// generic fp32 -> bf16 hi/lo pair conversion, optional transpose via strides,
// optional zero-pad on the contiguous (k) output dim.
// dst[b][i0][i1] (i1 contig, row stride d0) = src[b*sb + i0*s0 + i1*s1]
__global__ __launch_bounds__(256) void cvt_pair(
    const float* __restrict__ src, long s0, long s1, long sb,
    ushort* __restrict__ dh, ushort* __restrict__ dl, long d0, long db,
    int n0, int n1, int pad1, long total)
{
  long i = (long)blockIdx.x * 256 + threadIdx.x;
  if (i >= total) return;
  int wdt = n1 + pad1;
  int i1 = (int)(i % wdt); long rr = i / wdt;
  int i0 = (int)(rr % n0); int b = (int)(rr / n0);
  float f = 0.f;
  if (i1 < n1) f = src[(long)b * sb + (long)i0 * s0 + (long)i1 * s1];
  ushort h = f2bf(f);
  ushort l = f2bf(f - bf2f(h));
  long o = (long)b * db + (long)i0 * d0 + i1;
  dh[o] = h; dl[o] = l;
}

// concat w_qx|w_kx|w_vx -> Wc pair [768][2304]
__global__ __launch_bounds__(256) void concat_w_pair(
    const float* __restrict__ wq, const float* __restrict__ wk,
    const float* __restrict__ wv, ushort* __restrict__ dh, ushort* __restrict__ dl)
{
  int i = blockIdx.x * 256 + threadIdx.x;
  if (i >= 768 * 2304) return;
  int row = i / 2304;
  float f = (row < 256) ? wq[i] : (row < 512) ? wk[i - 256 * 2304] : wv[i - 512 * 2304];
  ushort h = f2bf(f);
  dh[i] = h; dl[i] = f2bf(f - bf2f(h));
}

// im2col (SAME 3x3, transposed layout) + convert: dst pair [cn*1600][2304]
__global__ __launch_bounds__(256) void im2colT(
    const float* __restrict__ xp, ushort* __restrict__ dh, ushort* __restrict__ dl,
    int nb0, long total)
{
  long i = (long)blockIdx.x * 256 + threadIdx.x;
  if (i >= total) return;
  int k = (int)(i % 2304); long rr = i / 2304;
  int q = (int)(rr % 1600); int nbl = (int)(rr / 1600);
  int c = k / 9, tap = k - c * 9;
  int dy = tap / 3, dx = tap - dy * 3;
  int qy = q / 40, qx = q - qy * 40;
  int y = qy + dy - 1, x = qx + dx - 1;
  float f = 0.f;
  if (y >= 0 && y < 40 && x >= 0 && x < 40)
    f = xp[(long)(nb0 + nbl) * 409600 + (long)c * 1600 + y * 40 + x];
  ushort h = f2bf(f);
  dh[i] = h; dl[i] = f2bf(f - bf2f(h));
}

// crop qkv channels 256..767 (SAME interior) -> VALID-indexed kx/vx (fp32)
__global__ __launch_bounds__(256) void crop_kv(
    const float* __restrict__ src, float* __restrict__ kx, float* __restrict__ vx,
    long total)
{
  long i = (long)blockIdx.x * 256 + threadIdx.x;
  if (i >= total) return;
  int d = (int)(i % 1444); long rr = i / 1444;
  int cc = (int)(rr % 512); int n = (int)(rr / 512);
  int yv = d / 38, xv = d - yv * 38;
  float v = src[(long)n * 1228800 + (long)(256 + cc) * 1600 + (yv + 1) * 40 + (xv + 1)];
  if (cc < 256) kx[(long)n * 369664 + (long)cc * 1444 + d] = v;
  else          vx[(long)n * 369664 + (long)(cc - 256) * 1444 + d] = v;
}

// step-1 uniform-h class tables: j<9 -> q_h1[j][a]; j==9 -> k_h1[a]; j==10 -> v_h1[a]
__global__ __launch_bounds__(64) void uniform_kv_kern(
    const float* __restrict__ h0, const float* __restrict__ w_qh,
    const float* __restrict__ w_kh, const float* __restrict__ w_vh,
    float* __restrict__ qh1, float* __restrict__ kh1, float* __restrict__ vh1)
{
  int a = blockIdx.x, j = blockIdx.y, t = threadIdx.x;
  const float* wsel = (j < 9) ? w_qh : (j == 9) ? w_kh : w_vh;
  bool dyok0 = true, dyok2 = true, dxok0 = true, dxok2 = true;
  if (j < 9) {
    int uy = j / 3, ux = j - uy * 3;
    dyok0 = (uy != 0); dyok2 = (uy != 2);
    dxok0 = (ux != 0); dxok2 = (ux != 2);
  }
  float acc = 0.f;
  for (int c = t; c < 256; c += 64) {
    const float* wp = wsel + a * 2304 + c * 9;
    float s = 0.f;
    #pragma unroll
    for (int dy = 0; dy < 3; ++dy) {
      if ((dy == 0 && !dyok0) || (dy == 2 && !dyok2)) continue;
      #pragma unroll
      for (int dx = 0; dx < 3; ++dx) {
        if ((dx == 0 && !dxok0) || (dx == 2 && !dxok2)) continue;
        s += wp[dy * 3 + dx];
      }
    }
    acc += s * h0[c];
  }
  #pragma unroll
  for (int o = 32; o; o >>= 1) acc += __shfl_down(acc, o);
  if (t == 0) {
    if (j < 9) qh1[j * 256 + a] = acc;
    else if (j == 9) kh1[a] = acc;
    else vh1[a] = acc;
  }
}

// fp32 in-place row softmax (used for the classed step-1 attention)
__global__ __launch_bounds__(256) void softmax_rows(float* __restrict__ p, int L)
{
  float* rp = p + (long)blockIdx.x * L;
  int t = threadIdx.x;
  __shared__ float redm[4], reds[4];
  float mx = -3.4e38f;
  for (int i = t; i < L; i += 256) mx = fmaxf(mx, rp[i]);
  #pragma unroll
  for (int o = 32; o; o >>= 1) mx = fmaxf(mx, __shfl_down(mx, o));
  if ((t & 63) == 0) redm[t >> 6] = mx;
  __syncthreads();
  mx = fmaxf(fmaxf(redm[0], redm[1]), fmaxf(redm[2], redm[3]));
  float s = 0.f;
  for (int i = t; i < L; i += 256) { float v = expf(rp[i] - mx); rp[i] = v; s += v; }
  #pragma unroll
  for (int o = 32; o; o >>= 1) s += __shfl_down(s, o);
  if ((t & 63) == 0) reds[t >> 6] = s;
  __syncthreads();
  float inv = 1.f / (reds[0] + reds[1] + reds[2] + reds[3]);
  for (int i = t; i < L; i += 256) rp[i] *= inv;
}

// softmax over 1444 logits -> bf16 pair rows padded to 1472
__global__ __launch_bounds__(256) void softmax_pair(
    const float* __restrict__ p, ushort* __restrict__ wh, ushort* __restrict__ wl)
{
  long row = blockIdx.x;
  const float* rp = p + row * 1444;
  ushort* oh = wh + row * 1472;
  ushort* ol = wl + row * 1472;
  int t = threadIdx.x;
  __shared__ float buf[1444];
  __shared__ float redm[4], reds[4];
  float mx = -3.4e38f;
  for (int i = t; i < 1444; i += 256) { float v = rp[i]; buf[i] = v; mx = fmaxf(mx, v); }
  #pragma unroll
  for (int o = 32; o; o >>= 1) mx = fmaxf(mx, __shfl_down(mx, o));
  if ((t & 63) == 0) redm[t >> 6] = mx;
  __syncthreads();
  mx = fmaxf(fmaxf(redm[0], redm[1]), fmaxf(redm[2], redm[3]));
  float s = 0.f;
  for (int i = t; i < 1444; i += 256) { float v = expf(buf[i] - mx); buf[i] = v; s += v; }
  #pragma unroll
  for (int o = 32; o; o >>= 1) s += __shfl_down(s, o);
  if ((t & 63) == 0) reds[t >> 6] = s;
  __syncthreads();
  float inv = 1.f / (reds[0] + reds[1] + reds[2] + reds[3]);
  for (int i = t; i < 1472; i += 256) {
    float v = (i < 1444) ? buf[i] * inv : 0.f;
    ushort h = f2bf(v);
    oh[i] = h; ol[i] = f2bf(v - bf2f(h));
  }
}

// gate input vector: [a10 ; v_h1] laid out [n][k512][u9]
__global__ __launch_bounds__(256) void build_vecb(
    const float* __restrict__ a10, const float* __restrict__ vh1,
    float* __restrict__ vecb)
{
  int i = blockIdx.x * 256 + threadIdx.x;
  if (i >= 8 * 512 * 9) return;
  int u = i % 9; int k = (i / 9) % 512; int n = i / 4608;
  vecb[i] = (k < 256) ? a10[n * 2304 + u * 256 + k] : vh1[k - 256];
}

// h1 = z*h0 + (1-z)*tanh(hpre), classed [n][hc][u9]
__global__ __launch_bounds__(256) void gate_ew(
    const float* __restrict__ zpre, const float* __restrict__ hpre,
    const float* __restrict__ h0, float* __restrict__ h1)
{
  int i = blockIdx.x * 256 + threadIdx.x;
  if (i >= 8 * 256 * 9) return;
  int hc = (i % 2304) / 9;
  float z = 1.f / (1.f + expf(-zpre[i]));
  float hv = tanhf(hpre[i]);
  h1[i] = z * h0[hc] + (1.f - z) * hv;
}

// classed im2col for step-2 VALID conv over piecewise-constant h1
__global__ __launch_bounds__(256) void build_G(
    const float* __restrict__ h1, float* __restrict__ G)
{
  int i = blockIdx.x * 256 + threadIdx.x;
  if (i >= 8 * 2304 * 9) return;
  int t = i % 9; int k = (i / 9) % 2304; int n = i / 20736;
  int c = k / 9, tap = k - c * 9, dy = tap / 3, dx = tap - dy * 3;
  int ty = t / 3, tx = t - ty * 3;
  int uy = (ty == 0) ? (dy == 0 ? 0 : 1) : (ty == 2) ? (dy == 2 ? 2 : 1) : 1;
  int ux = (tx == 0) ? (dx == 0 ? 0 : 1) : (tx == 2) ? (dx == 2 ? 2 : 1) : 1;
  G[i] = h1[n * 2304 + c * 9 + uy * 3 + ux];
}

// step-2 (a=0,b=1) classed attention (9 logits, mult {1,36,1}^2) ->
// bf16 pair columns 512..767 of xaT
__global__ __launch_bounds__(256) void attn_b1(
    const float* __restrict__ qkv, const float* __restrict__ khc,
    const float* __restrict__ vhc, ushort* __restrict__ xaTh, ushort* __restrict__ xaTl)
{
  __shared__ float ks[2304];
  __shared__ float vs[2304];
  int n = blockIdx.y;
  int q = blockIdx.x * 256 + threadIdx.x;
  const float* kp = khc + n * 2304;
  const float* vp = vhc + n * 2304;
  for (int i = threadIdx.x; i < 2304; i += 256) { ks[i] = kp[i]; vs[i] = vp[i]; }
  __syncthreads();
  bool act = (q < 1600);
  float L[9] = {0.f, 0.f, 0.f, 0.f, 0.f, 0.f, 0.f, 0.f, 0.f};
  const float* qp = qkv + (long)n * 1228800 + q;
  for (int c = 0; c < 256; ++c) {
    float qv = act ? qp[(long)c * 1600] : 0.f;
    #pragma unroll
    for (int t = 0; t < 9; ++t) L[t] += qv * ks[c * 9 + t];
  }
  float mx = L[0];
  #pragma unroll
  for (int t = 1; t < 9; ++t) mx = fmaxf(mx, L[t]);
  float e[9]; float Z = 0.f;
  #pragma unroll
  for (int t = 0; t < 9; ++t) {
    float m = ((t / 3) == 1 ? 36.f : 1.f) * ((t % 3) == 1 ? 36.f : 1.f);
    e[t] = m * expf(L[t] - mx);
    Z += e[t];
  }
  float inv = 1.f / Z;
  #pragma unroll
  for (int t = 0; t < 9; ++t) e[t] *= inv;
  if (!act) return;
  ushort* oh = xaTh + (long)n * 1228800 + (long)q * 768 + 512;
  ushort* ol = xaTl + (long)n * 1228800 + (long)q * 768 + 512;
  for (int p = 0; p < 256; ++p) {
    float s = 0.f;
    #pragma unroll
    for (int t = 0; t < 9; ++t) s += e[t] * vs[p * 9 + t];
    ushort h = f2bf(s);
    oh[p] = h; ol[p] = f2bf(s - bf2f(h));
  }
}

// small fp32 GEMM (round-1 gemm64) for the tiny classed ops
__global__ __launch_bounds__(256) void gemm64(
    const float* __restrict__ A, long sAm, long sAk, long sAb,
    const float* __restrict__ B, long sBk, long sBn, long sBb,
    float* __restrict__ Y, long sYm, long sYn, long sYb,
    const float* __restrict__ bias,
    int M, int Nn, int K, int aMc, int bNc)
{
  __shared__ __align__(16) float As[16][68];
  __shared__ __align__(16) float Bs[16][68];
  const int bz = blockIdx.z;
  A += (long)bz * sAb; B += (long)bz * sBb; Y += (long)bz * sYb;
  const int m0 = blockIdx.y * 64, n0 = blockIdx.x * 64;
  const int tid = threadIdx.x;
  const int tx = tid & 15, ty = tid >> 4;
  float acc[4][4] = {{0.f,0.f,0.f,0.f},{0.f,0.f,0.f,0.f},{0.f,0.f,0.f,0.f},{0.f,0.f,0.f,0.f}};
  for (int k0 = 0; k0 < K; k0 += 16) {
    if (aMc) {
      #pragma unroll
      for (int i = tid; i < 1024; i += 256) {
        int m = i & 63, kk = i >> 6;
        int mm = m0 + m, kg = k0 + kk;
        As[kk][m] = (mm < M && kg < K) ? A[(long)mm * sAm + (long)kg * sAk] : 0.f;
      }
    } else {
      #pragma unroll
      for (int i = tid; i < 1024; i += 256) {
        int kk = i & 15, m = i >> 4;
        int mm = m0 + m, kg = k0 + kk;
        As[kk][m] = (mm < M && kg < K) ? A[(long)mm * sAm + (long)kg * sAk] : 0.f;
      }
    }
    if (bNc) {
      #pragma unroll
      for (int i = tid; i < 1024; i += 256) {
        int n = i & 63, kk = i >> 6;
        int nn = n0 + n, kg = k0 + kk;
        Bs[kk][n] = (nn < Nn && kg < K) ? B[(long)kg * sBk + (long)nn * sBn] : 0.f;
      }
    } else {
      #pragma unroll
      for (int i = tid; i < 1024; i += 256) {
        int kk = i & 15, n = i >> 4;
        int nn = n0 + n, kg = k0 + kk;
        Bs[kk][n] = (nn < Nn && kg < K) ? B[(long)kg * sBk + (long)nn * sBn] : 0.f;
      }
    }
    __syncthreads();
    #pragma unroll
    for (int kk = 0; kk < 16; ++kk) {
      float4 av = *(const float4*)&As[kk][ty * 4];
      float4 bv = *(const float4*)&Bs[kk][tx * 4];
      float a0 = av.x, a1 = av.y, a2 = av.z, a3 = av.w;
      float b0 = bv.x, b1 = bv.y, b2 = bv.z, b3 = bv.w;
      acc[0][0] += a0*b0; acc[0][1] += a0*b1; acc[0][2] += a0*b2; acc[0][3] += a0*b3;
      acc[1][0] += a1*b0; acc[1][1] += a1*b1; acc[1][2] += a1*b2; acc[1][3] += a1*b3;
      acc[2][0] += a2*b0; acc[2][1] += a2*b1; acc[2][2] += a2*b2; acc[2][3] += a2*b3;
      acc[3][0] += a3*b0; acc[3][1] += a3*b1; acc[3][2] += a3*b2; acc[3][3] += a3*b3;
    }
    __syncthreads();
  }
  #pragma unroll
  for (int i = 0; i < 4; ++i) {
    int mm = m0 + ty * 4 + i;
    if (mm >= M) continue;
    float bb = bias ? bias[mm] : 0.f;
    #pragma unroll
    for (int j = 0; j < 4; ++j) {
      int nn = n0 + tx * 4 + j;
      if (nn < Nn) Y[(long)mm * sYm + (long)nn * sYn] = acc[i][j] + bb;
    }
  }
}

// ---------------------------------------------------------------------------
extern "C" void kernel_launch(void* const* d_in, const int* in_sizes, int n_in,
                              void* d_out, int out_size, void* d_ws, size_t ws_size,
                              hipStream_t stream)
{
  const float* x     = (const float*)d_in[0];
  const float* h0    = (const float*)d_in[1];
  const float* w_px  = (const float*)d_in[2];
  const float* b_px  = (const float*)d_in[3];
  const float* w_qx  = (const float*)d_in[4];
  const float* w_qh  = (const float*)d_in[5];
  const float* w_kx  = (const float*)d_in[6];
  const float* w_kh  = (const float*)d_in[7];
  const float* w_vx  = (const float*)d_in[8];
  const float* w_vh  = (const float*)d_in[9];
  const float* w_z   = (const float*)d_in[10];
  const float* b_z   = (const float*)d_in[11];
  const float* w_h   = (const float*)d_in[12];
  const float* b_h   = (const float*)d_in[13];
  const float* w_out = (const float*)d_in[14];
  const float* b_out = (const float*)d_in[15];
  float* out = (float*)d_out;

  // ---- byte-granular workspace allocator (256 B aligned) ----
  char* base = (char*)d_ws;
  size_t off = 0;
  auto alloc = [&](size_t bytes) -> char* {
    off = (off + 255) & ~(size_t)255;
    char* p = base + off; off += bytes; return p;
  };
  float*  qkv   = (float*)alloc(39321600);           // [8][768][1600] f32
  float*  kx    = (float*)alloc(11829248);           // [8][256][1444]
  float*  vx    = (float*)alloc(11829248);
  float*  xp    = (float*)alloc(13107200);           // [8][256][1600]
  ushort* xaTh  = (ushort*)alloc(19660800);          // [8][1600][768]
  ushort* xaTl  = (ushort*)alloc(19660800);
  ushort* xTh   = (ushort*)alloc(3276800);           // [12800][128]
  ushort* xTl   = (ushort*)alloc(3276800);
  ushort* Wch   = (ushort*)alloc(3538944);           // [768][2304]
  ushort* Wcl   = (ushort*)alloc(3538944);
  ushort* wpxh  = (ushort*)alloc(65536);             // [256][128]
  ushort* wpxl  = (ushort*)alloc(65536);
  ushort* wouth = (ushort*)alloc(393216);            // [256][768]
  ushort* woutl = (ushort*)alloc(393216);
  ushort* qTh   = (ushort*)alloc(6553600);           // [8][1600][256]
  ushort* qTl   = (ushort*)alloc(6553600);
  ushort* kxTh  = (ushort*)alloc(5914624);           // [8][1444][256]
  ushort* kxTl  = (ushort*)alloc(5914624);
  ushort* vxph  = (ushort*)alloc(6029312);           // [8][256][1472]
  ushort* vxpl  = (ushort*)alloc(6029312);
  float*  qh1   = (float*)alloc(9216);
  float*  kh1   = (float*)alloc(1024);
  float*  vh1   = (float*)alloc(1024);
  float*  L0    = (float*)alloc(415872);             // [8][9][1444]
  float*  a10   = (float*)alloc(73728);
  float*  vecb  = (float*)alloc(147456);
  float*  zpre  = (float*)alloc(73728);
  float*  hpre  = (float*)alloc(73728);
  float*  h1    = (float*)alloc(73728);
  float*  G     = (float*)alloc(663552);
  float*  khc   = (float*)alloc(73728);
  float*  vhc   = (float*)alloc(73728);
  off = (off + 255) & ~(size_t)255;
  char* chunk = base + off;
  long avail = (long)ws_size - (long)off;
  if (avail < 0) avail = 0;
  int cn = (int)(avail / 14745600L); if (cn < 1) cn = 1; if (cn > 8) cn = 8;
  int an = (int)(avail / 18662400L); if (an < 1) an = 1; if (an > 8) an = 8;

  auto mg = [&](dim3 grid,
                const ushort* Ah, const ushort* Al, long sAb,
                const ushort* Bh, const ushort* Bl, long sBb,
                float* Y, long sYb, long sYm, int nPer, long sYb2,
                ushort* Yh, ushort* Yl, long sYpb, long sYpm,
                const float* bias, int M, int Nn, int K) {
    mgemm<<<grid, dim3(256), 0, stream>>>(Ah, Al, sAb, Bh, Bl, sBb,
        Y, sYb, sYm, nPer, sYb2, Yh, Yl, sYpb, sYpm, bias, M, Nn, K);
  };
  auto g64 = [&](dim3 grid,
                 const float* A, long sAm, long sAk, long sAb,
                 const float* B, long sBk, long sBn, long sBb,
                 float* Y, long sYm, long sYn, long sYb,
                 const float* bias, int M, int Nn, int K, int aMc, int bNc) {
    gemm64<<<grid, dim3(256), 0, stream>>>(A, sAm, sAk, sAb, B, sBk, sBn, sBb,
        Y, sYm, sYn, sYb, bias, M, Nn, K, aMc, bNc);
  };
  const int BIG = 0x40000000;

  // ---- 1) weight/input conversions ----
  concat_w_pair<<<dim3(6912), dim3(256), 0, stream>>>(w_qx, w_kx, w_vx, Wch, Wcl);
  cvt_pair<<<dim3(128), dim3(256), 0, stream>>>(w_px, 128, 1, 0, wpxh, wpxl, 128, 0, 256, 128, 0, 32768);
  cvt_pair<<<dim3(768), dim3(256), 0, stream>>>(w_out, 768, 1, 0, wouth, woutl, 768, 0, 256, 768, 0, 196608);
  cvt_pair<<<dim3(6400), dim3(256), 0, stream>>>(x, 1, 1600, 204800, xTh, xTl, 128, 204800, 1600, 128, 0, 1638400);

  // ---- 2) xp = w_px.x + b_px (MFMA), then xaT cols 0..255 ----
  mg(dim3(2, 100, 1), wpxh, wpxl, 0, xTh, xTl, 0,
     xp, 0, 1600, 1600, 409600, nullptr, nullptr, 0, 0, b_px, 256, 12800, 128);
  cvt_pair<<<dim3(12800), dim3(256), 0, stream>>>(xp, 1, 1600, 409600, xaTh, xaTl, 768, 1228800, 1600, 256, 0, 3276800);

  // ---- 3) fused qkv conv (MFMA, batch-chunked) ----
  {
    ushort* ich = (ushort*)chunk;
    for (int nb0 = 0; nb0 < 8; nb0 += cn) {
      int c = (8 - nb0 < cn) ? (8 - nb0) : cn;
      ushort* icl = ich + (long)c * 3686400;
      long tot = (long)c * 3686400;
      im2colT<<<dim3((unsigned)((tot + 255) / 256)), dim3(256), 0, stream>>>(xp, ich, icl, nb0, tot);
      int nt = (1600 * c + 127) / 128;
      mg(dim3(6, nt, 1), Wch, Wcl, 0, ich, icl, 0,
         qkv + (long)nb0 * 1228800, 0, 1600, 1600, 1228800,
         nullptr, nullptr, 0, 0, nullptr, 768, 1600 * c, 2304);
    }
  }
  crop_kv<<<dim3(23104), dim3(256), 0, stream>>>(qkv, kx, vx, (long)8 * 512 * 1444);

  // ---- 4) attention operand conversions ----
  cvt_pair<<<dim3(12800), dim3(256), 0, stream>>>(qkv, 1, 1600, 1228800, qTh, qTl, 256, 409600, 1600, 256, 0, 3276800);
  cvt_pair<<<dim3(11552), dim3(256), 0, stream>>>(kx, 1, 1444, 369664, kxTh, kxTl, 256, 369664, 1444, 256, 0, 2957312);
  cvt_pair<<<dim3(11776), dim3(256), 0, stream>>>(vx, 1444, 1, 369664, vxph, vxpl, 1472, 376832, 256, 1444, 28, 3014656);

  // ---- 5) step-1 classed tables, gates, classed step-2 attention ----
  uniform_kv_kern<<<dim3(256, 11), dim3(64), 0, stream>>>(h0, w_qh, w_kh, w_vh, qh1, kh1, vh1);
  g64(dim3(23, 1, 8), qh1, 256, 1, 0, kx, 1444, 1, 369664,
      L0, 1444, 1, 12996, nullptr, 9, 1444, 256, 0, 1);
  softmax_rows<<<dim3(72), dim3(256), 0, stream>>>(L0, 1444);
  g64(dim3(1, 4, 8), vx, 1444, 1, 369664, L0, 1, 1444, 12996,
      a10, 1, 256, 2304, nullptr, 256, 9, 1444, 0, 0);
  build_vecb<<<dim3(144), dim3(256), 0, stream>>>(a10, vh1, vecb);
  g64(dim3(1, 4, 8), w_z, 512, 1, 0, vecb, 9, 1, 4608,
      zpre, 9, 1, 2304, b_z, 256, 9, 512, 0, 1);
  g64(dim3(1, 4, 8), w_h, 512, 1, 0, vecb, 9, 1, 4608,
      hpre, 9, 1, 2304, b_h, 256, 9, 512, 0, 1);
  gate_ew<<<dim3(72), dim3(256), 0, stream>>>(zpre, hpre, h0, h1);
  build_G<<<dim3(648), dim3(256), 0, stream>>>(h1, G);
  g64(dim3(1, 4, 8), w_kh, 2304, 1, 0, G, 9, 1, 20736,
      khc, 9, 1, 2304, nullptr, 256, 9, 2304, 0, 1);
  g64(dim3(1, 4, 8), w_vh, 2304, 1, 0, G, 9, 1, 20736,
      vhc, 9, 1, 2304, nullptr, 256, 9, 2304, 0, 1);
  attn_b1<<<dim3(7, 8), dim3(256), 0, stream>>>(qkv, khc, vhc, xaTh, xaTl);

  // ---- 6) step-2 (0,0) full attention (MFMA logits + softmax + MFMA PV) ----
  {
    float*  scL = (float*)chunk;
    for (int nb0 = 0; nb0 < 8; nb0 += an) {
      int c = (8 - nb0 < an) ? (8 - nb0) : an;
      ushort* wth = (ushort*)(chunk + (long)c * 9241600);
      ushort* wtl = wth + (long)c * 2355200;
      mg(dim3(13, 12, c), qTh + (long)nb0 * 409600, qTl + (long)nb0 * 409600, 409600,
         kxTh + (long)nb0 * 369664, kxTl + (long)nb0 * 369664, 369664,
         scL, 2310400, 1444, BIG, 0, nullptr, nullptr, 0, 0, nullptr, 1600, 1444, 256);
      softmax_pair<<<dim3(c * 1600), dim3(256), 0, stream>>>(scL, wth, wtl);
      mg(dim3(13, 2, c), wth, wtl, 2355200,
         vxph + (long)nb0 * 376832, vxpl + (long)nb0 * 376832, 376832,
         nullptr, 0, 0, BIG, 0,
         xaTh + (long)nb0 * 1228800 + 256, xaTl + (long)nb0 * 1228800 + 256,
         1228800, 768, nullptr, 1600, 256, 1472);
    }
  }

  // ---- 7) out = w_out . xaT + b_out (MFMA, batch-flattened N) ----
  mg(dim3(2, 100, 1), wouth, woutl, 0, xaTh, xaTl, 0,
     out, 0, 1600, 1600, 409600, nullptr, nullptr, 0, 0, b_out, 256, 12800, 768);
}

// Round 4
// 1364.479 us; speedup vs baseline: 3.6976x; 1.4677x over previous
//
#include <hip/hip_runtime.h>
#include <math.h>

// ---------------------------------------------------------------------------
// 2-step recurrent attention cell, N=8, I=128, C=Hc=A=P=O=256, H=W=40
// (Q=1600), VALID 3x3 -> 38x38 (D=1444). fp32 reference.
//
// Exact algebraic reductions (rounds 0-2): step1 h uniform -> classed tables;
// step2 (0,1) attention collapses to 9 key classes; dead branches removed.
// R3: heavy GEMMs on MFMA via split-bf16 (f32 = hi+lo bf16, 3 products).
// R4: tiny classed gemm64s (32-block latency chains, ~300us each) replaced by
// fused shape-specialized kernels; crop+convert fused; gemm64 deleted.
// ---------------------------------------------------------------------------

typedef __attribute__((ext_vector_type(8))) short bf8;   // 8 bf16 (4 VGPRs)
typedef __attribute__((ext_vector_type(4))) float f4;

__device__ __forceinline__ ushort f2bf(float f) {
  unsigned u = __float_as_uint(f);
  u += 0x7fffu + ((u >> 16) & 1u);
  return (ushort)(u >> 16);
}
__device__ __forceinline__ float bf2f(ushort h) {
  return __uint_as_float(((unsigned)h) << 16);
}

// ---------------- MFMA split-bf16 GEMM ----------------
// C[m][n] = sum_k A[m][k]*B[n][k]  (both operands k-contig "row" layout)
// A planes [M][K], B planes [N][K], K multiple of 32 (zero-padded by producer).
// 128x128 tile, 4 waves, wave = 64x64 quadrant of 16x16x32 MFMA tiles.
// Store: fp32 mode (Yh==null): addr = bz*sYb + (nn/nPer)*sYb2 + mm*sYm + nn%nPer
//        pair mode: bf16 hi/lo planes at bz*sYpb + mm*sYpm + nn.
__global__ __launch_bounds__(256) void mgemm(
    const ushort* __restrict__ Ah, const ushort* __restrict__ Al, long sAb,
    const ushort* __restrict__ Bh, const ushort* __restrict__ Bl, long sBb,
    float* __restrict__ Y, long sYb, long sYm, int nPer, long sYb2,
    ushort* __restrict__ Yh, ushort* __restrict__ Yl, long sYpb, long sYpm,
    const float* __restrict__ bias, int M, int Nn, int K)
{
  __shared__ ushort Ash[128][40], Asl[128][40], Bsh[128][40], Bsl[128][40];
  const int bz = blockIdx.z;
  Ah += (long)bz * sAb; Al += (long)bz * sAb;
  Bh += (long)bz * sBb; Bl += (long)bz * sBb;
  const int m0 = blockIdx.x * 128, n0 = blockIdx.y * 128;
  const int t = threadIdx.x;
  const int lane = t & 63, w = t >> 6;
  const int wm = (w & 1) * 64, wn = (w >> 1) * 64;
  const int r = lane & 15, qd = lane >> 4;
  const int row0 = t >> 2, seg = t & 3;
  f4 acc[4][4];
  #pragma unroll
  for (int i = 0; i < 4; ++i)
    #pragma unroll
    for (int j = 0; j < 4; ++j) acc[i][j] = (f4){0.f, 0.f, 0.f, 0.f};

  for (int kc = 0; kc < K; kc += 32) {
    #pragma unroll
    for (int half = 0; half < 2; ++half) {
      int row = row0 + half * 64;
      {
        int mm = m0 + row;
        uint4 vh = make_uint4(0,0,0,0), vl = make_uint4(0,0,0,0);
        if (mm < M) {
          size_t o = (size_t)mm * K + kc + seg * 8;
          vh = *(const uint4*)(Ah + o);
          vl = *(const uint4*)(Al + o);
        }
        *(uint4*)&Ash[row][seg * 8] = vh;
        *(uint4*)&Asl[row][seg * 8] = vl;
      }
      {
        int nn = n0 + row;
        uint4 vh = make_uint4(0,0,0,0), vl = make_uint4(0,0,0,0);
        if (nn < Nn) {
          size_t o = (size_t)nn * K + kc + seg * 8;
          vh = *(const uint4*)(Bh + o);
          vl = *(const uint4*)(Bl + o);
        }
        *(uint4*)&Bsh[row][seg * 8] = vh;
        *(uint4*)&Bsl[row][seg * 8] = vl;
      }
    }
    __syncthreads();
    bf8 ahf[4], alf[4], bhf[4], blf[4];
    #pragma unroll
    for (int mt = 0; mt < 4; ++mt) {
      ahf[mt] = *(const bf8*)&Ash[wm + mt * 16 + r][qd * 8];
      alf[mt] = *(const bf8*)&Asl[wm + mt * 16 + r][qd * 8];
      bhf[mt] = *(const bf8*)&Bsh[wn + mt * 16 + r][qd * 8];
      blf[mt] = *(const bf8*)&Bsl[wn + mt * 16 + r][qd * 8];
    }
    #pragma unroll
    for (int mt = 0; mt < 4; ++mt)
      #pragma unroll
      for (int nt = 0; nt < 4; ++nt) {
        acc[mt][nt] = __builtin_amdgcn_mfma_f32_16x16x32_bf16(ahf[mt], bhf[nt], acc[mt][nt], 0, 0, 0);
        acc[mt][nt] = __builtin_amdgcn_mfma_f32_16x16x32_bf16(ahf[mt], blf[nt], acc[mt][nt], 0, 0, 0);
        acc[mt][nt] = __builtin_amdgcn_mfma_f32_16x16x32_bf16(alf[mt], bhf[nt], acc[mt][nt], 0, 0, 0);
      }
    __syncthreads();
  }
  #pragma unroll
  for (int mt = 0; mt < 4; ++mt)
    #pragma unroll
    for (int nt = 0; nt < 4; ++nt) {
      int nn = n0 + wn + nt * 16 + r;
      #pragma unroll
      for (int e = 0; e < 4; ++e) {
        int mm = m0 + wm + mt * 16 + qd * 4 + e;
        if (mm >= M || nn >= Nn) continue;
        float v = acc[mt][nt][e];
        if (Yh) {
          size_t o = (size_t)bz * sYpb + (size_t)mm * sYpm + nn;
          ushort h = f2bf(v);
          Yh[o] = h;
          Yl[o] = f2bf(v - bf2f(h));
        } else {
          int nb = nn / nPer, nq = nn - nb * nPer;
          if (bias) v += bias[mm];
          Y[(size_t)bz * sYb + (size_t)nb * sYb2 + (size_t)mm * sYm + nq] = v;
        }
      }
    }
}

// generic fp32 -> bf16 hi/lo pair conversion (strided read, contig write)
__global__ __launch_bounds__(256) void cvt_pair(
    const float* __restrict__ src, long s0, long s1, long sb,
    ushort* __restrict__ dh, ushort* __restrict__ dl, long d0, long db,
    int n0, int n1, int pad1, long total)
{
  long i = (long)blockIdx.x * 256 + threadIdx.x;
  if (i >= total) return;
  int wdt = n1 + pad1;
  int i1 = (int)(i % wdt); long rr = i / wdt;
  int i0 = (int)(rr % n0); int b = (int)(rr / n0);
  float f = 0.f;
  if (i1 < n1) f = src[(long)b * sb + (long)i0 * s0 + (long)i1 * s1];
  ushort h = f2bf(f);
  ushort l = f2bf(f - bf2f(h));
  long o = (long)b * db + (long)i0 * d0 + i1;
  dh[o] = h; dl[o] = l;
}

// concat w_qx|w_kx|w_vx -> Wc pair [768][2304]
__global__ __launch_bounds__(256) void concat_w_pair(
    const float* __restrict__ wq, const float* __restrict__ wk,
    const float* __restrict__ wv, ushort* __restrict__ dh, ushort* __restrict__ dl)
{
  int i = blockIdx.x * 256 + threadIdx.x;
  if (i >= 768 * 2304) return;
  int row = i / 2304;
  float f = (row < 256) ? wq[i] : (row < 512) ? wk[i - 256 * 2304] : wv[i - 512 * 2304];
  ushort h = f2bf(f);
  dh[i] = h; dl[i] = f2bf(f - bf2f(h));
}

// im2col (SAME 3x3, transposed layout) + convert: dst pair [cn*1600][2304]
__global__ __launch_bounds__(256) void im2colT(
    const float* __restrict__ xp, ushort* __restrict__ dh, ushort* __restrict__ dl,
    int nb0, long total)
{
  long i = (long)blockIdx.x * 256 + threadIdx.x;
  if (i >= total) return;
  int k = (int)(i % 2304); long rr = i / 2304;
  int q = (int)(rr % 1600); int nbl = (int)(rr / 1600);
  int c = k / 9, tap = k - c * 9;
  int dy = tap / 3, dx = tap - dy * 3;
  int qy = q / 40, qx = q - qy * 40;
  int y = qy + dy - 1, x = qx + dx - 1;
  float f = 0.f;
  if (y >= 0 && y < 40 && x >= 0 && x < 40)
    f = xp[(long)(nb0 + nbl) * 409600 + (long)c * 1600 + y * 40 + x];
  ushort h = f2bf(f);
  dh[i] = h; dl[i] = f2bf(f - bf2f(h));
}

// fused crop (SAME interior -> VALID) + convert:
//  cc<256 : kx fp32 [n][c][1444]  +  kxT pair [n][1444][256]
//  cc>=256: vxp pair [n][256][1472] (d-padded with zeros)
__global__ __launch_bounds__(256) void crop_cvt(
    const float* __restrict__ qkv, float* __restrict__ kx,
    ushort* __restrict__ kxTh, ushort* __restrict__ kxTl,
    ushort* __restrict__ vxph, ushort* __restrict__ vxpl, long total)
{
  long i = (long)blockIdx.x * 256 + threadIdx.x;
  if (i >= total) return;
  int dp = (int)(i % 1472); long rr = i / 1472;
  int cc = (int)(rr % 512); int n = (int)(rr / 512);
  float v = 0.f;
  if (dp < 1444) {
    int yv = dp / 38, xv = dp - yv * 38;
    v = qkv[(long)n * 1228800 + (long)(256 + cc) * 1600 + (yv + 1) * 40 + (xv + 1)];
  }
  ushort h = f2bf(v), l = f2bf(v - bf2f(h));
  if (cc < 256) {
    if (dp < 1444) {
      kx[(long)n * 369664 + (long)cc * 1444 + dp] = v;
      long o = (long)n * 369664 + (long)dp * 256 + cc;
      kxTh[o] = h; kxTl[o] = l;
    }
  } else {
    long o = (long)n * 376832 + (long)(cc - 256) * 1472 + dp;
    vxph[o] = h; vxpl[o] = l;
  }
}

// step-1 uniform-h class tables: j<9 -> q_h1[j][a]; j==9 -> k_h1[a]; j==10 -> v_h1[a]
__global__ __launch_bounds__(64) void uniform_kv_kern(
    const float* __restrict__ h0, const float* __restrict__ w_qh,
    const float* __restrict__ w_kh, const float* __restrict__ w_vh,
    float* __restrict__ qh1, float* __restrict__ kh1, float* __restrict__ vh1)
{
  int a = blockIdx.x, j = blockIdx.y, t = threadIdx.x;
  const float* wsel = (j < 9) ? w_qh : (j == 9) ? w_kh : w_vh;
  bool dyok0 = true, dyok2 = true, dxok0 = true, dxok2 = true;
  if (j < 9) {
    int uy = j / 3, ux = j - uy * 3;
    dyok0 = (uy != 0); dyok2 = (uy != 2);
    dxok0 = (ux != 0); dxok2 = (ux != 2);
  }
  float acc = 0.f;
  for (int c = t; c < 256; c += 64) {
    const float* wp = wsel + a * 2304 + c * 9;
    float s = 0.f;
    #pragma unroll
    for (int dy = 0; dy < 3; ++dy) {
      if ((dy == 0 && !dyok0) || (dy == 2 && !dyok2)) continue;
      #pragma unroll
      for (int dx = 0; dx < 3; ++dx) {
        if ((dx == 0 && !dxok0) || (dx == 2 && !dxok2)) continue;
        s += wp[dy * 3 + dx];
      }
    }
    acc += s * h0[c];
  }
  #pragma unroll
  for (int o = 32; o; o >>= 1) acc += __shfl_down(acc, o);
  if (t == 0) {
    if (j < 9) qh1[j * 256 + a] = acc;
    else if (j == 9) kh1[a] = acc;
    else vh1[a] = acc;
  }
}

// L0[n][u][d] = sum_c qh1[u][c] * kx[n][c][d]   grid(6,8), thread=d
__global__ __launch_bounds__(256) void l0_logits(
    const float* __restrict__ qh1, const float* __restrict__ kx,
    float* __restrict__ L0)
{
  __shared__ float qs[2304];
  int db = blockIdx.x, n = blockIdx.y;
  for (int i = threadIdx.x; i < 2304; i += 256) qs[i] = qh1[i];
  __syncthreads();
  int d = db * 256 + threadIdx.x;
  if (d >= 1444) return;
  const float* kp = kx + (long)n * 369664 + d;
  float acc[9] = {0.f,0.f,0.f,0.f,0.f,0.f,0.f,0.f,0.f};
  for (int c = 0; c < 256; ++c) {
    float kv = kp[(long)c * 1444];
    #pragma unroll
    for (int u = 0; u < 9; ++u) acc[u] += qs[u * 256 + c] * kv;
  }
  for (int u = 0; u < 9; ++u) L0[n * 12996 + u * 1444 + d] = acc[u];
}

// fp32 in-place row softmax (step-1 classed attention rows)
__global__ __launch_bounds__(256) void softmax_rows(float* __restrict__ p, int L)
{
  float* rp = p + (long)blockIdx.x * L;
  int t = threadIdx.x;
  __shared__ float redm[4], reds[4];
  float mx = -3.4e38f;
  for (int i = t; i < L; i += 256) mx = fmaxf(mx, rp[i]);
  #pragma unroll
  for (int o = 32; o; o >>= 1) mx = fmaxf(mx, __shfl_down(mx, o));
  if ((t & 63) == 0) redm[t >> 6] = mx;
  __syncthreads();
  mx = fmaxf(fmaxf(redm[0], redm[1]), fmaxf(redm[2], redm[3]));
  float s = 0.f;
  for (int i = t; i < L; i += 256) { float v = expf(rp[i] - mx); rp[i] = v; s += v; }
  #pragma unroll
  for (int o = 32; o; o >>= 1) s += __shfl_down(s, o);
  if ((t & 63) == 0) reds[t >> 6] = s;
  __syncthreads();
  float inv = 1.f / (reds[0] + reds[1] + reds[2] + reds[3]);
  for (int i = t; i < L; i += 256) rp[i] *= inv;
}

// a10[n][u][p] = sum_d wt[n][u][d] * v[n][p][d]  (v from bf16 pair, 8-wide)
__global__ __launch_bounds__(256) void a10_pv(
    const float* __restrict__ L0, const ushort* __restrict__ vxph,
    const ushort* __restrict__ vxpl, float* __restrict__ a10)
{
  int u = blockIdx.x, n = blockIdx.y;   // grid(9,8)
  __shared__ float wts[1472];
  const float* wrow = L0 + n * 12996 + u * 1444;
  for (int i = threadIdx.x; i < 1472; i += 256) wts[i] = (i < 1444) ? wrow[i] : 0.f;
  __syncthreads();
  int p = threadIdx.x;
  const ushort* vh = vxph + (long)n * 376832 + (long)p * 1472;
  const ushort* vl = vxpl + (long)n * 376832 + (long)p * 1472;
  float acc = 0.f;
  for (int d8 = 0; d8 < 1472; d8 += 8) {
    uint4 hv = *(const uint4*)(vh + d8);
    uint4 lv = *(const uint4*)(vl + d8);
    unsigned hw[4] = {hv.x, hv.y, hv.z, hv.w};
    unsigned lw[4] = {lv.x, lv.y, lv.z, lv.w};
    #pragma unroll
    for (int j = 0; j < 4; ++j) {
      float f0 = bf2f((ushort)(hw[j] & 0xffff)) + bf2f((ushort)(lw[j] & 0xffff));
      float f1 = bf2f((ushort)(hw[j] >> 16))   + bf2f((ushort)(lw[j] >> 16));
      acc += wts[d8 + j * 2] * f0 + wts[d8 + j * 2 + 1] * f1;
    }
  }
  a10[n * 2304 + u * 256 + p] = acc;
}

// gates fused: zpre/hpre = W.[a10;vh1]+b, h1 = z*h0+(1-z)*tanh(hpre)
// block per n, thread per hc; vecb value depends only on (k,u) -> LDS broadcast
__global__ __launch_bounds__(256) void gates_k(
    const float* __restrict__ a10, const float* __restrict__ vh1,
    const float* __restrict__ w_z, const float* __restrict__ b_z,
    const float* __restrict__ w_h, const float* __restrict__ b_h,
    const float* __restrict__ h0, float* __restrict__ h1)
{
  int n = blockIdx.x;
  __shared__ float as[2304], vs[256];
  for (int i = threadIdx.x; i < 2304; i += 256) as[i] = a10[n * 2304 + i];
  if (threadIdx.x < 256) vs[threadIdx.x] = vh1[threadIdx.x];
  __syncthreads();
  int hc = threadIdx.x;
  const float* wz = w_z + hc * 512;
  const float* wh = w_h + hc * 512;
  float az[9], ah[9];
  float bz = b_z[hc], bh = b_h[hc];
  #pragma unroll
  for (int u = 0; u < 9; ++u) { az[u] = bz; ah[u] = bh; }
  for (int k = 0; k < 256; ++k) {
    float wzv = wz[k], whv = wh[k];
    #pragma unroll
    for (int u = 0; u < 9; ++u) {
      float vv = as[u * 256 + k];
      az[u] += wzv * vv; ah[u] += whv * vv;
    }
  }
  float sz = 0.f, sh = 0.f;
  for (int k = 0; k < 256; ++k) { float vv = vs[k]; sz += wz[256 + k] * vv; sh += wh[256 + k] * vv; }
  float h0v = h0[hc];
  #pragma unroll
  for (int u = 0; u < 9; ++u) {
    float z = 1.f / (1.f + expf(-(az[u] + sz)));
    float hv = tanhf(ah[u] + sh);
    h1[n * 2304 + hc * 9 + u] = z * h0v + (1.f - z) * hv;
  }
}

// khc/vhc fused: classed VALID conv over piecewise-constant h1.
// block per (u,n); LDS class-gather of 2304 values, then per-thread 2304-dot.
__global__ __launch_bounds__(256) void khvh_k(
    const float* __restrict__ h1, const float* __restrict__ w_kh,
    const float* __restrict__ w_vh, float* __restrict__ khc, float* __restrict__ vhc)
{
  int u = blockIdx.x, n = blockIdx.y;   // grid(9,8)
  int ty = u / 3, tx = u - ty * 3;
  __shared__ float Gs[2304];
  for (int k = threadIdx.x; k < 2304; k += 256) {
    int c = k / 9, tap = k - c * 9, dy = tap / 3, dx = tap - dy * 3;
    int uy = (ty == 0) ? (dy == 0 ? 0 : 1) : (ty == 2) ? (dy == 2 ? 2 : 1) : 1;
    int ux = (tx == 0) ? (dx == 0 ? 0 : 1) : (tx == 2) ? (dx == 2 ? 2 : 1) : 1;
    Gs[k] = h1[n * 2304 + c * 9 + uy * 3 + ux];
  }
  __syncthreads();
  int hc = threadIdx.x;
  const float* wk = w_kh + hc * 2304;
  const float* wv = w_vh + hc * 2304;
  float ak = 0.f, av = 0.f;
  for (int k = 0; k < 2304; ++k) { float g = Gs[k]; ak += wk[k] * g; av += wv[k] * g; }
  khc[n * 2304 + hc * 9 + u] = ak;
  vhc[n * 2304 + hc * 9 + u] = av;
}

// softmax over 1444 logits -> bf16 pair rows padded to 1472
__global__ __launch_bounds__(256) void softmax_pair(
    const float* __restrict__ p, ushort* __restrict__ wh, ushort* __restrict__ wl)
{
  long row = blockIdx.x;
  const float* rp = p + row * 1444;
  ushort* oh = wh + row * 1472;
  ushort* ol = wl + row * 1472;
  int t = threadIdx.x;
  __shared__ float buf[1444];
  __shared__ float redm[4], reds[4];
  float mx = -3.4e38f;
  for (int i = t; i < 1444; i += 256) { float v = rp[i]; buf[i] = v; mx = fmaxf(mx, v); }
  #pragma unroll
  for (int o = 32; o; o >>= 1) mx = fmaxf(mx, __shfl_down(mx, o));
  if ((t & 63) == 0) redm[t >> 6] = mx;
  __syncthreads();
  mx = fmaxf(fmaxf(redm[0], redm[1]), fmaxf(redm[2], redm[3]));
  float s = 0.f;
  for (int i = t; i < 1444; i += 256) { float v = expf(buf[i] - mx); buf[i] = v; s += v; }
  #pragma unroll
  for (int o = 32; o; o >>= 1) s += __shfl_down(s, o);
  if ((t & 63) == 0) reds[t >> 6] = s;
  __syncthreads();
  float inv = 1.f / (reds[0] + reds[1] + reds[2] + reds[3]);
  for (int i = t; i < 1472; i += 256) {
    float v = (i < 1444) ? buf[i] * inv : 0.f;
    ushort h = f2bf(v);
    oh[i] = h; ol[i] = f2bf(v - bf2f(h));
  }
}

// step-2 (a=0,b=1) classed attention (9 logits, mult {1,36,1}^2) ->
// bf16 pair columns 512..767 of xaT
__global__ __launch_bounds__(256) void attn_b1(
    const float* __restrict__ qkv, const float* __restrict__ khc,
    const float* __restrict__ vhc, ushort* __restrict__ xaTh, ushort* __restrict__ xaTl)
{
  __shared__ float ks[2304];
  __shared__ float vs[2304];
  int n = blockIdx.y;
  int q = blockIdx.x * 256 + threadIdx.x;
  const float* kp = khc + n * 2304;
  const float* vp = vhc + n * 2304;
  for (int i = threadIdx.x; i < 2304; i += 256) { ks[i] = kp[i]; vs[i] = vp[i]; }
  __syncthreads();
  bool act = (q < 1600);
  float L[9] = {0.f, 0.f, 0.f, 0.f, 0.f, 0.f, 0.f, 0.f, 0.f};
  const float* qp = qkv + (long)n * 1228800 + q;
  for (int c = 0; c < 256; ++c) {
    float qv = act ? qp[(long)c * 1600] : 0.f;
    #pragma unroll
    for (int t = 0; t < 9; ++t) L[t] += qv * ks[c * 9 + t];
  }
  float mx = L[0];
  #pragma unroll
  for (int t = 1; t < 9; ++t) mx = fmaxf(mx, L[t]);
  float e[9]; float Z = 0.f;
  #pragma unroll
  for (int t = 0; t < 9; ++t) {
    float m = ((t / 3) == 1 ? 36.f : 1.f) * ((t % 3) == 1 ? 36.f : 1.f);
    e[t] = m * expf(L[t] - mx);
    Z += e[t];
  }
  float inv = 1.f / Z;
  #pragma unroll
  for (int t = 0; t < 9; ++t) e[t] *= inv;
  if (!act) return;
  ushort* oh = xaTh + (long)n * 1228800 + (long)q * 768 + 512;
  ushort* ol = xaTl + (long)n * 1228800 + (long)q * 768 + 512;
  for (int p = 0; p < 256; ++p) {
    float s = 0.f;
    #pragma unroll
    for (int t = 0; t < 9; ++t) s += e[t] * vs[p * 9 + t];
    ushort h = f2bf(s);
    oh[p] = h; ol[p] = f2bf(s - bf2f(h));
  }
}

// ---------------------------------------------------------------------------
extern "C" void kernel_launch(void* const* d_in, const int* in_sizes, int n_in,
                              void* d_out, int out_size, void* d_ws, size_t ws_size,
                              hipStream_t stream)
{
  const float* x     = (const float*)d_in[0];
  const float* h0    = (const float*)d_in[1];
  const float* w_px  = (const float*)d_in[2];
  const float* b_px  = (const float*)d_in[3];
  const float* w_qx  = (const float*)d_in[4];
  const float* w_qh  = (const float*)d_in[5];
  const float* w_kx  = (const float*)d_in[6];
  const float* w_kh  = (const float*)d_in[7];
  const float* w_vx  = (const float*)d_in[8];
  const float* w_vh  = (const float*)d_in[9];
  const float* w_z   = (const float*)d_in[10];
  const float* b_z   = (const float*)d_in[11];
  const float* w_h   = (const float*)d_in[12];
  const float* b_h   = (const float*)d_in[13];
  const float* w_out = (const float*)d_in[14];
  const float* b_out = (const float*)d_in[15];
  float* out = (float*)d_out;

  char* base = (char*)d_ws;
  size_t off = 0;
  auto alloc = [&](size_t bytes) -> char* {
    off = (off + 255) & ~(size_t)255;
    char* p = base + off; off += bytes; return p;
  };
  float*  qkv   = (float*)alloc(39321600);           // [8][768][1600] f32
  float*  kx    = (float*)alloc(11829248);           // [8][256][1444]
  float*  xp    = (float*)alloc(13107200);           // [8][256][1600]
  ushort* xaTh  = (ushort*)alloc(19660800);          // [8][1600][768]
  ushort* xaTl  = (ushort*)alloc(19660800);
  ushort* xTh   = (ushort*)alloc(3276800);           // [12800][128]
  ushort* xTl   = (ushort*)alloc(3276800);
  ushort* Wch   = (ushort*)alloc(3538944);           // [768][2304]
  ushort* Wcl   = (ushort*)alloc(3538944);
  ushort* wpxh  = (ushort*)alloc(65536);             // [256][128]
  ushort* wpxl  = (ushort*)alloc(65536);
  ushort* wouth = (ushort*)alloc(393216);            // [256][768]
  ushort* woutl = (ushort*)alloc(393216);
  ushort* qTh   = (ushort*)alloc(6553600);           // [8][1600][256]
  ushort* qTl   = (ushort*)alloc(6553600);
  ushort* kxTh  = (ushort*)alloc(5914624);           // [8][1444][256]
  ushort* kxTl  = (ushort*)alloc(5914624);
  ushort* vxph  = (ushort*)alloc(6029312);           // [8][256][1472]
  ushort* vxpl  = (ushort*)alloc(6029312);
  float*  qh1   = (float*)alloc(9216);
  float*  kh1   = (float*)alloc(1024);
  float*  vh1   = (float*)alloc(1024);
  float*  L0    = (float*)alloc(415872);             // [8][9][1444]
  float*  a10   = (float*)alloc(73728);
  float*  h1    = (float*)alloc(73728);
  float*  khc   = (float*)alloc(73728);
  float*  vhc   = (float*)alloc(73728);
  off = (off + 255) & ~(size_t)255;
  char* chunk = base + off;
  long avail = (long)ws_size - (long)off;
  if (avail < 0) avail = 0;
  int cn = (int)(avail / 14745600L); if (cn < 1) cn = 1; if (cn > 8) cn = 8;
  int an = (int)(avail / 18662400L); if (an < 1) an = 1; if (an > 8) an = 8;

  auto mg = [&](dim3 grid,
                const ushort* Ah, const ushort* Al, long sAb,
                const ushort* Bh, const ushort* Bl, long sBb,
                float* Y, long sYb, long sYm, int nPer, long sYb2,
                ushort* Yh, ushort* Yl, long sYpb, long sYpm,
                const float* bias, int M, int Nn, int K) {
    mgemm<<<grid, dim3(256), 0, stream>>>(Ah, Al, sAb, Bh, Bl, sBb,
        Y, sYb, sYm, nPer, sYb2, Yh, Yl, sYpb, sYpm, bias, M, Nn, K);
  };
  const int BIG = 0x40000000;

  // ---- 1) weight/input conversions ----
  concat_w_pair<<<dim3(6912), dim3(256), 0, stream>>>(w_qx, w_kx, w_vx, Wch, Wcl);
  cvt_pair<<<dim3(128), dim3(256), 0, stream>>>(w_px, 128, 1, 0, wpxh, wpxl, 128, 0, 256, 128, 0, 32768);
  cvt_pair<<<dim3(768), dim3(256), 0, stream>>>(w_out, 768, 1, 0, wouth, woutl, 768, 0, 256, 768, 0, 196608);
  cvt_pair<<<dim3(6400), dim3(256), 0, stream>>>(x, 1, 1600, 204800, xTh, xTl, 128, 204800, 1600, 128, 0, 1638400);

  // ---- 2) xp = w_px.x + b_px (MFMA), then xaT cols 0..255 ----
  mg(dim3(2, 100, 1), wpxh, wpxl, 0, xTh, xTl, 0,
     xp, 0, 1600, 1600, 409600, nullptr, nullptr, 0, 0, b_px, 256, 12800, 128);
  cvt_pair<<<dim3(12800), dim3(256), 0, stream>>>(xp, 1, 1600, 409600, xaTh, xaTl, 768, 1228800, 1600, 256, 0, 3276800);

  // ---- 3) fused qkv conv (MFMA, batch-chunked) ----
  {
    ushort* ich = (ushort*)chunk;
    for (int nb0 = 0; nb0 < 8; nb0 += cn) {
      int c = (8 - nb0 < cn) ? (8 - nb0) : cn;
      ushort* icl = ich + (long)c * 3686400;
      long tot = (long)c * 3686400;
      im2colT<<<dim3((unsigned)((tot + 255) / 256)), dim3(256), 0, stream>>>(xp, ich, icl, nb0, tot);
      int nt = (1600 * c + 127) / 128;
      mg(dim3(6, nt, 1), Wch, Wcl, 0, ich, icl, 0,
         qkv + (long)nb0 * 1228800, 0, 1600, 1600, 1228800,
         nullptr, nullptr, 0, 0, nullptr, 768, 1600 * c, 2304);
    }
  }
  // fused crop + convert (kx f32, kxT pair, vxp pair)
  crop_cvt<<<dim3(23552), dim3(256), 0, stream>>>(qkv, kx, kxTh, kxTl, vxph, vxpl,
                                                  (long)8 * 512 * 1472);
  // qT pair for logits GEMM
  cvt_pair<<<dim3(12800), dim3(256), 0, stream>>>(qkv, 1, 1600, 1228800, qTh, qTl, 256, 409600, 1600, 256, 0, 3276800);

  // ---- 4) classed section (fused, parallel kernels; no tiny GEMMs) ----
  uniform_kv_kern<<<dim3(256, 11), dim3(64), 0, stream>>>(h0, w_qh, w_kh, w_vh, qh1, kh1, vh1);
  l0_logits<<<dim3(6, 8), dim3(256), 0, stream>>>(qh1, kx, L0);
  softmax_rows<<<dim3(72), dim3(256), 0, stream>>>(L0, 1444);
  a10_pv<<<dim3(9, 8), dim3(256), 0, stream>>>(L0, vxph, vxpl, a10);
  gates_k<<<dim3(8), dim3(256), 0, stream>>>(a10, vh1, w_z, b_z, w_h, b_h, h0, h1);
  khvh_k<<<dim3(9, 8), dim3(256), 0, stream>>>(h1, w_kh, w_vh, khc, vhc);
  attn_b1<<<dim3(7, 8), dim3(256), 0, stream>>>(qkv, khc, vhc, xaTh, xaTl);

  // ---- 5) step-2 (0,0) full attention (MFMA logits + softmax + MFMA PV) ----
  {
    float* scL = (float*)chunk;
    for (int nb0 = 0; nb0 < 8; nb0 += an) {
      int c = (8 - nb0 < an) ? (8 - nb0) : an;
      ushort* wth = (ushort*)(chunk + (long)c * 9241600);
      ushort* wtl = wth + (long)c * 2355200;
      mg(dim3(13, 12, c), qTh + (long)nb0 * 409600, qTl + (long)nb0 * 409600, 409600,
         kxTh + (long)nb0 * 369664, kxTl + (long)nb0 * 369664, 369664,
         scL, 2310400, 1444, BIG, 0, nullptr, nullptr, 0, 0, nullptr, 1600, 1444, 256);
      softmax_pair<<<dim3(c * 1600), dim3(256), 0, stream>>>(scL, wth, wtl);
      mg(dim3(13, 2, c), wth, wtl, 2355200,
         vxph + (long)nb0 * 376832, vxpl + (long)nb0 * 376832, 376832,
         nullptr, 0, 0, BIG, 0,
         xaTh + (long)nb0 * 1228800 + 256, xaTl + (long)nb0 * 1228800 + 256,
         1228800, 768, nullptr, 1600, 256, 1472);
    }
  }

  // ---- 6) out = w_out . xaT + b_out (MFMA, batch-flattened N) ----
  mg(dim3(2, 100, 1), wouth, woutl, 0, xaTh, xaTl, 0,
     out, 0, 1600, 1600, 409600, nullptr, nullptr, 0, 0, b_out, 256, 12800, 768);
}